// Round 1
// baseline (822.260 us; speedup 1.0000x reference)
//
#include <hip/hip_runtime.h>
#include <hip/hip_bf16.h>

#define N_NODES_C 50000
#define N_EDGES_C 800000
#define IN_DIM_C  128
#define HID_C     64
#define HEADS_C   4
#define OUT_DIM_C 20
#define NUM_GRAPHS_C 64
#define NEG_SLOPE 0.2f

__device__ __forceinline__ float lrelu(float t){ return t > 0.f ? t : NEG_SLOPE*t; }
__device__ __forceinline__ float elu1(float t){ return t > 0.f ? t : __expf(t)-1.f; }

// ---------------- CSR build ----------------
__global__ void hist_kernel(const int* __restrict__ ei, int* __restrict__ cursor){
  int e = blockIdx.x*256 + threadIdx.x;
  if (e < N_EDGES_C) atomicAdd(&cursor[ei[N_EDGES_C + e]], 1);
}

__global__ __launch_bounds__(1024) void scan_kernel(int* __restrict__ cursor, int* __restrict__ offsets){
  __shared__ int totals[1024];
  int tid = threadIdx.x;
  const int chunk = (N_NODES_C + 1023)/1024; // 49
  int s = tid*chunk; int e = min(s+chunk, N_NODES_C);
  int sum = 0;
  for(int i=s;i<e;i++) sum += cursor[i];
  totals[tid] = sum;
  __syncthreads();
  for(int off=1; off<1024; off<<=1){
    int t = (tid>=off) ? totals[tid-off] : 0;
    __syncthreads();
    totals[tid] += t;
    __syncthreads();
  }
  int run = totals[tid] - sum; // exclusive prefix of this thread's chunk
  for(int i=s;i<e;i++){
    int c = cursor[i];
    offsets[i] = run;
    cursor[i]  = run;   // cursor becomes the fill pointer
    run += c;
  }
  if(tid==1023) offsets[N_NODES_C] = totals[1023];
}

__global__ void fill_kernel(const int* __restrict__ ei, int* __restrict__ cursor, int* __restrict__ adj){
  int e = blockIdx.x*256 + threadIdx.x;
  if (e >= N_EDGES_C) return;
  int sI = ei[e]; int d = ei[N_EDGES_C + e];
  int p = atomicAdd(&cursor[d], 1);
  adj[p] = sI;
}

// ---------------- conv1 linear + attention alphas ----------------
// h1 = x @ W1^T  [N,256]; as1/ad1 [N,4]
__global__ __launch_bounds__(256) void lin1_kernel(const float* __restrict__ x, const float* __restrict__ W1,
    const float* __restrict__ aS, const float* __restrict__ aD,
    float* __restrict__ h1, float* __restrict__ as1, float* __restrict__ ad1){
  __shared__ float xs[16*IN_DIM_C]; // 8 KB
  int tid = threadIdx.x;
  int nb = blockIdx.x*16;
  {
    const float4* xsrc = (const float4*)(x + (size_t)nb*IN_DIM_C);
    float4* xdst = (float4*)xs;
    #pragma unroll
    for(int i=tid;i<16*IN_DIM_C/4;i+=256) xdst[i] = xsrc[i];
  }
  __syncthreads();
  int o = tid; int head = o>>6;
  float acc[16];
  #pragma unroll
  for(int n=0;n<16;n++) acc[n]=0.f;
  const float4* Wv = (const float4*)(W1 + (size_t)o*IN_DIM_C);
  for(int k4=0;k4<IN_DIM_C/4;k4++){
    float4 w = Wv[k4];
    #pragma unroll
    for(int n=0;n<16;n++){
      float4 xv = ((const float4*)(xs + n*IN_DIM_C))[k4];
      acc[n] = fmaf(w.x,xv.x, fmaf(w.y,xv.y, fmaf(w.z,xv.z, fmaf(w.w,xv.w, acc[n]))));
    }
  }
  float asw = aS[o], adw = aD[o];
  #pragma unroll
  for(int n=0;n<16;n++){
    float h = acc[n];
    h1[(size_t)(nb+n)*256 + o] = h;
    float ps = h*asw, pd = h*adw;
    #pragma unroll
    for(int d=32; d>=1; d>>=1){ ps += __shfl_xor(ps, d); pd += __shfl_xor(pd, d); }
    if((o&63)==0){ as1[(nb+n)*4 + head] = ps; ad1[(nb+n)*4 + head] = pd; }
  }
}

// ---------------- conv1 aggregation (softmax over incoming edges, fused) ----------------
__global__ __launch_bounds__(256) void agg1_kernel(const int* __restrict__ offsets, const int* __restrict__ adj,
    const float* __restrict__ h1, const float* __restrict__ as1, const float* __restrict__ ad1,
    const float* __restrict__ b1, float* __restrict__ out1){
  int v = blockIdx.x;
  int tid = threadIdx.x; int o = tid; int head = o>>6; int wv = tid>>6; int lane = tid&63;
  int start = offsets[v], end = offsets[v+1];
  float4 ad4 = ((const float4*)ad1)[v];
  float4 as4 = ((const float4*)as1)[v];
  // phase A: per-head max over all incoming edges + self-loop
  float m0 = lrelu(as4.x + ad4.x);
  float m1 = lrelu(as4.y + ad4.y);
  float m2 = lrelu(as4.z + ad4.z);
  float m3 = lrelu(as4.w + ad4.w);
  for(int i=start+tid; i<end; i+=256){
    int s = adj[i];
    float4 a = ((const float4*)as1)[s];
    m0 = fmaxf(m0, lrelu(a.x + ad4.x));
    m1 = fmaxf(m1, lrelu(a.y + ad4.y));
    m2 = fmaxf(m2, lrelu(a.z + ad4.z));
    m3 = fmaxf(m3, lrelu(a.w + ad4.w));
  }
  #pragma unroll
  for(int d=32; d>=1; d>>=1){
    m0 = fmaxf(m0, __shfl_xor(m0, d));
    m1 = fmaxf(m1, __shfl_xor(m1, d));
    m2 = fmaxf(m2, __shfl_xor(m2, d));
    m3 = fmaxf(m3, __shfl_xor(m3, d));
  }
  __shared__ float mred[4][4];
  if(lane==0){ mred[wv][0]=m0; mred[wv][1]=m1; mred[wv][2]=m2; mred[wv][3]=m3; }
  __syncthreads();
  float mfin = fmaxf(fmaxf(mred[0][head], mred[1][head]), fmaxf(mred[2][head], mred[3][head]));
  float adh = head==0?ad4.x : head==1?ad4.y : head==2?ad4.z : ad4.w;
  float ash = head==0?as4.x : head==1?as4.y : head==2?as4.z : as4.w;
  // phase B: exp + weighted accumulate (serial over edge list; all 256 ch in parallel)
  float wself = __expf(lrelu(ash+adh) - mfin);
  float denom = wself;
  float acc = wself * h1[(size_t)v*256 + o];
  int sNext = (start<end)? adj[start] : 0;
  for(int i=start;i<end;i++){
    int s = sNext;
    sNext = (i+1<end)? adj[i+1] : 0;
    float a = as1[s*4 + head];         // wave-uniform -> broadcast
    float w = __expf(lrelu(a + adh) - mfin);
    denom += w;
    acc = fmaf(w, h1[(size_t)s*256 + o], acc);  // coalesced 1KB/edge
  }
  float r = acc/(denom + 1e-16f) + b1[o];
  out1[(size_t)v*256 + o] = elu1(r);
}

// ---------------- conv2 linear + alphas ----------------
// h2 = out1 @ W2^T [N,64]
__global__ __launch_bounds__(256) void lin2_kernel(const float* __restrict__ in, const float* __restrict__ W2,
    const float* __restrict__ aS, const float* __restrict__ aD,
    float* __restrict__ h2, float* __restrict__ as2, float* __restrict__ ad2){
  __shared__ float xs[16*256]; // 16 KB
  int tid=threadIdx.x;
  int nb = blockIdx.x*16;
  {
    const float4* xsrc = (const float4*)(in + (size_t)nb*256);
    float4* xdst = (float4*)xs;
    #pragma unroll
    for(int i=tid;i<16*256/4;i+=256) xdst[i] = xsrc[i];
  }
  __syncthreads();
  int o = tid&63; int slot = tid>>6;
  float acc[4];
  #pragma unroll
  for(int j=0;j<4;j++) acc[j]=0.f;
  const float4* Wv = (const float4*)(W2 + (size_t)o*256);
  for(int k4=0;k4<64;k4++){
    float4 w = Wv[k4];
    #pragma unroll
    for(int j=0;j<4;j++){
      float4 xv = ((const float4*)(xs + (slot*4+j)*256))[k4];
      acc[j] = fmaf(w.x,xv.x, fmaf(w.y,xv.y, fmaf(w.z,xv.z, fmaf(w.w,xv.w, acc[j]))));
    }
  }
  float asw = aS[o], adw = aD[o];
  #pragma unroll
  for(int j=0;j<4;j++){
    int n = nb + slot*4 + j;
    float h = acc[j];
    h2[(size_t)n*64 + o] = h;
    float ps = h*asw, pd = h*adw;
    #pragma unroll
    for(int d=32; d>=1; d>>=1){ ps += __shfl_xor(ps,d); pd += __shfl_xor(pd,d); }
    if(o==0){ as2[n]=ps; ad2[n]=pd; }
  }
}

// ---------------- conv2 aggregation (1 head, C=64 -> one wave per node) ----------------
__global__ __launch_bounds__(256) void agg2_kernel(const int* __restrict__ offsets, const int* __restrict__ adj,
    const float* __restrict__ h2, const float* __restrict__ as2, const float* __restrict__ ad2,
    const float* __restrict__ b2, float* __restrict__ out2){
  int wv = threadIdx.x>>6; int lane = threadIdx.x&63;
  int v = blockIdx.x*4 + wv;
  if (v >= N_NODES_C) return;
  int start=offsets[v], end=offsets[v+1];
  float adv = ad2[v], asv = as2[v];
  float m = lrelu(asv+adv);
  for(int i=start+lane;i<end;i+=64){
    m = fmaxf(m, lrelu(as2[adj[i]] + adv));
  }
  #pragma unroll
  for(int d=32; d>=1; d>>=1) m = fmaxf(m, __shfl_xor(m,d));
  float wself = __expf(lrelu(asv+adv) - m);
  float denom = wself;
  float acc = wself * h2[(size_t)v*64+lane];
  int sNext = (start<end)? adj[start]:0;
  for(int i=start;i<end;i++){
    int s=sNext; sNext = (i+1<end)? adj[i+1]:0;
    float w = __expf(lrelu(as2[s]+adv) - m);
    denom += w;
    acc = fmaf(w, h2[(size_t)s*64+lane], acc);
  }
  float r = acc/(denom+1e-16f) + b2[lane];
  out2[(size_t)v*64+lane] = elu1(r);
}

// ---------------- segment-max pool over batch + FC ----------------
__global__ __launch_bounds__(256) void pool_fc_kernel(const float* __restrict__ out2, const int* __restrict__ batch,
    const float* __restrict__ fcW, const float* __restrict__ fcb, float* __restrict__ out){
  int g = blockIdx.x;
  int tid=threadIdx.x; int c = tid&63; int slot = tid>>6;
  // lower_bound(batch, g) and lower_bound(batch, g+1)  (batch sorted)
  int lo=0, hi=N_NODES_C;
  while(lo<hi){ int mid=(lo+hi)>>1; if(batch[mid] < g) lo=mid+1; else hi=mid; }
  int start=lo;
  hi=N_NODES_C;
  while(lo<hi){ int mid=(lo+hi)>>1; if(batch[mid] < g+1) lo=mid+1; else hi=mid; }
  int end=lo;
  float mm = -INFINITY;
  #pragma unroll 4
  for(int n=start+slot; n<end; n+=4) mm = fmaxf(mm, out2[(size_t)n*64+c]);
  __shared__ float sred[4][64];
  sred[slot][c]=mm;
  __syncthreads();
  if(tid < 64){
    float p = fmaxf(fmaxf(sred[0][tid],sred[1][tid]), fmaxf(sred[2][tid],sred[3][tid]));
    sred[0][tid]=p;
  }
  __syncthreads();
  if(tid < OUT_DIM_C){
    float acc = fcb[tid];
    #pragma unroll
    for(int cc=0;cc<64;cc++) acc = fmaf(sred[0][cc], fcW[tid*64+cc], acc);
    out[g*OUT_DIM_C + tid] = acc;
  }
}

extern "C" void kernel_launch(void* const* d_in, const int* in_sizes, int n_in,
                              void* d_out, int out_size, void* d_ws, size_t ws_size,
                              hipStream_t stream) {
  const float* x   = (const float*)d_in[0];
  const int*   ei  = (const int*)  d_in[1];
  const int*   bat = (const int*)  d_in[2];
  const float* W1  = (const float*)d_in[3];
  const float* aS1 = (const float*)d_in[4];
  const float* aD1 = (const float*)d_in[5];
  const float* b1  = (const float*)d_in[6];
  const float* W2  = (const float*)d_in[7];
  const float* aS2 = (const float*)d_in[8];
  const float* aD2 = (const float*)d_in[9];
  const float* b2  = (const float*)d_in[10];
  const float* fcW = (const float*)d_in[11];
  const float* fcb = (const float*)d_in[12];
  float* out = (float*)d_out;

  // workspace layout (256B aligned); h2/as2/ad2/out2 alias dead conv1 buffers
  char* w = (char*)d_ws;
  size_t off = 0;
  auto alloc = [&](size_t bytes)->char* {
    char* p = w + off; off = (off + bytes + 255) & ~(size_t)255; return p;
  };
  int* offsets = (int*)alloc((N_NODES_C+1)*sizeof(int));
  int* cursor  = (int*)alloc((size_t)N_NODES_C*sizeof(int));
  int* adj     = (int*)alloc((size_t)N_EDGES_C*sizeof(int));
  float* h1    = (float*)alloc((size_t)N_NODES_C*256*sizeof(float));
  float* as1   = (float*)alloc((size_t)N_NODES_C*4*sizeof(float));
  float* ad1   = (float*)alloc((size_t)N_NODES_C*4*sizeof(float));
  float* out1  = (float*)alloc((size_t)N_NODES_C*256*sizeof(float));
  float* h2  = h1;   // h1 dead after agg1
  float* as2 = as1;  // dead after agg1
  float* ad2 = ad1;
  float* out2 = out1; // out1 dead after lin2
  (void)ws_size; (void)in_sizes; (void)n_in; (void)out_size;

  hipMemsetAsync(cursor, 0, (size_t)N_NODES_C*sizeof(int), stream);
  hist_kernel<<<N_EDGES_C/256, 256, 0, stream>>>(ei, cursor);
  scan_kernel<<<1, 1024, 0, stream>>>(cursor, offsets);
  fill_kernel<<<N_EDGES_C/256, 256, 0, stream>>>(ei, cursor, adj);

  lin1_kernel<<<N_NODES_C/16, 256, 0, stream>>>(x, W1, aS1, aD1, h1, as1, ad1);
  agg1_kernel<<<N_NODES_C, 256, 0, stream>>>(offsets, adj, h1, as1, ad1, b1, out1);
  lin2_kernel<<<N_NODES_C/16, 256, 0, stream>>>(out1, W2, aS2, aD2, h2, as2, ad2);
  agg2_kernel<<<N_NODES_C/4, 256, 0, stream>>>(offsets, adj, h2, as2, ad2, b2, out2);
  pool_fc_kernel<<<NUM_GRAPHS_C, 256, 0, stream>>>(out2, bat, fcW, fcb, out);
}

// Round 2
// 590.156 us; speedup vs baseline: 1.3933x; 1.3933x over previous
//
#include <hip/hip_runtime.h>
#include <hip/hip_bf16.h>

#define N_NODES_C 50000
#define N_EDGES_C 800000
#define IN_DIM_C  128
#define HID_C     64
#define HEADS_C   4
#define OUT_DIM_C 20
#define NUM_GRAPHS_C 64
#define NEG_SLOPE 0.2f
#define SCAN_BLOCKS 196   // ceil(50000/256)

__device__ __forceinline__ float lrelu(float t){ return t > 0.f ? t : NEG_SLOPE*t; }
__device__ __forceinline__ float elu1(float t){ return t > 0.f ? t : __expf(t)-1.f; }
__device__ __forceinline__ ushort f2bf(float f){ // RNE f32->bf16
  unsigned u = __float_as_uint(f);
  return (ushort)((u + 0x7fffu + ((u>>16)&1u)) >> 16);
}
__device__ __forceinline__ float bflo(unsigned u){ return __uint_as_float(u<<16); }
__device__ __forceinline__ float bfhi(unsigned u){ return __uint_as_float(u & 0xffff0000u); }

// ---------------- CSR build ----------------
__global__ void hist_kernel(const int* __restrict__ ei, int* __restrict__ cursor){
  int e = blockIdx.x*256 + threadIdx.x;
  if (e < N_EDGES_C) atomicAdd(&cursor[ei[N_EDGES_C + e]], 1);
}

// per-block sums of counts
__global__ __launch_bounds__(256) void reduce_counts(const int* __restrict__ cursor, int* __restrict__ blockSums){
  int i = blockIdx.x*256 + threadIdx.x;
  int c = (i < N_NODES_C) ? cursor[i] : 0;
  #pragma unroll
  for(int d=32; d>=1; d>>=1) c += __shfl_xor(c, d);
  __shared__ int s4[4];
  int lane = threadIdx.x & 63, wv = threadIdx.x >> 6;
  if(lane==0) s4[wv] = c;
  __syncthreads();
  if(threadIdx.x==0) blockSums[blockIdx.x] = s4[0]+s4[1]+s4[2]+s4[3];
}

// exclusive scan of the 196 block sums (single block)
__global__ __launch_bounds__(256) void scan_sums(int* __restrict__ blockSums){
  __shared__ int sh[256];
  int t = threadIdx.x;
  int v = (t < SCAN_BLOCKS) ? blockSums[t] : 0;
  sh[t] = v; __syncthreads();
  #pragma unroll
  for(int off=1; off<256; off<<=1){
    int u = (t>=off) ? sh[t-off] : 0;
    __syncthreads();
    sh[t] += u;
    __syncthreads();
  }
  if(t < SCAN_BLOCKS) blockSums[t] = sh[t] - v;   // exclusive
}

// per-block exclusive scan + add block prefix; writes offsets and resets cursor to fill-pointers
__global__ __launch_bounds__(256) void scan_block(int* __restrict__ cursor, const int* __restrict__ blockSums,
                                                  int* __restrict__ offsets){
  __shared__ int sh[256];
  int t = threadIdx.x;
  int i = blockIdx.x*256 + t;
  int c = (i < N_NODES_C) ? cursor[i] : 0;
  sh[t] = c; __syncthreads();
  #pragma unroll
  for(int off=1; off<256; off<<=1){
    int u = (t>=off) ? sh[t-off] : 0;
    __syncthreads();
    sh[t] += u;
    __syncthreads();
  }
  int excl = sh[t] - c;
  int pref = blockSums[blockIdx.x] + excl;
  if(i < N_NODES_C){
    offsets[i] = pref;
    cursor[i]  = pref;
    if(i == N_NODES_C-1) offsets[N_NODES_C] = pref + c;
  }
}

__global__ void fill_kernel(const int* __restrict__ ei, int* __restrict__ cursor, int* __restrict__ adj){
  int e = blockIdx.x*256 + threadIdx.x;
  if (e >= N_EDGES_C) return;
  int sI = ei[e]; int d = ei[N_EDGES_C + e];
  int p = atomicAdd(&cursor[d], 1);
  adj[p] = sI;
}

// ---------------- conv1 linear + attention alphas ----------------
// h1(bf16) = x @ W1^T  [N,256]; as1/ad1 [N,4] (f32, from unrounded h)
__global__ __launch_bounds__(256) void lin1_kernel(const float* __restrict__ x, const float* __restrict__ W1,
    const float* __restrict__ aS, const float* __restrict__ aD,
    ushort* __restrict__ h1, float* __restrict__ as1, float* __restrict__ ad1){
  __shared__ float xs[16*IN_DIM_C]; // 8 KB
  int tid = threadIdx.x;
  int nb = blockIdx.x*16;
  {
    const float4* xsrc = (const float4*)(x + (size_t)nb*IN_DIM_C);
    float4* xdst = (float4*)xs;
    #pragma unroll
    for(int i=tid;i<16*IN_DIM_C/4;i+=256) xdst[i] = xsrc[i];
  }
  __syncthreads();
  int o = tid; int head = o>>6;
  float acc[16];
  #pragma unroll
  for(int n=0;n<16;n++) acc[n]=0.f;
  const float4* Wv = (const float4*)(W1 + (size_t)o*IN_DIM_C);
  for(int k4=0;k4<IN_DIM_C/4;k4++){
    float4 w = Wv[k4];
    #pragma unroll
    for(int n=0;n<16;n++){
      float4 xv = ((const float4*)(xs + n*IN_DIM_C))[k4];
      acc[n] = fmaf(w.x,xv.x, fmaf(w.y,xv.y, fmaf(w.z,xv.z, fmaf(w.w,xv.w, acc[n]))));
    }
  }
  float asw = aS[o], adw = aD[o];
  #pragma unroll
  for(int n=0;n<16;n++){
    float h = acc[n];
    h1[(size_t)(nb+n)*256 + o] = f2bf(h);
    float ps = h*asw, pd = h*adw;
    #pragma unroll
    for(int d=32; d>=1; d>>=1){ ps += __shfl_xor(ps, d); pd += __shfl_xor(pd, d); }
    if((o&63)==0){ as1[(nb+n)*4 + head] = ps; ad1[(nb+n)*4 + head] = pd; }
  }
}

// ---------------- conv1 aggregation: 1 wave per node, no max pass ----------------
__global__ __launch_bounds__(256) void agg1_kernel(const int* __restrict__ offsets, const int* __restrict__ adj,
    const ushort* __restrict__ h1, const float* __restrict__ as1, const float* __restrict__ ad1,
    const float* __restrict__ b1, float* __restrict__ out1){
  int wv = threadIdx.x>>6, lane = threadIdx.x&63;
  int v = blockIdx.x*4 + wv;              // 50000 % 4 == 0
  int head = lane>>4;                     // lane's 4 channels all in this head
  int start = offsets[v], end = offsets[v+1];
  float adh = ad1[(v<<2)+head];
  float ash = as1[(v<<2)+head];
  float wself = __expf(lrelu(ash+adh));
  float denom = wself;
  unsigned long long base = ((unsigned long long)v<<8) + (lane<<2);
  uint2 ps = *(const uint2*)(h1 + base);
  float acc0 = wself*bflo(ps.x), acc1 = wself*bfhi(ps.x);
  float acc2 = wself*bflo(ps.y), acc3 = wself*bfhi(ps.y);
  int sNext = adj[start];                 // adj has E+1 slots; value unused if start==end
  for(int i=start;i<end;i++){
    int s = sNext;
    sNext = adj[i+1];
    float a = as1[(s<<2)+head];
    float w = __expf(lrelu(a+adh));
    denom += w;
    uint2 p = *(const uint2*)(h1 + (((unsigned long long)s<<8) + (lane<<2)));
    acc0 = fmaf(w, bflo(p.x), acc0);
    acc1 = fmaf(w, bfhi(p.x), acc1);
    acc2 = fmaf(w, bflo(p.y), acc2);
    acc3 = fmaf(w, bfhi(p.y), acc3);
  }
  float inv = 1.f/(denom + 1e-16f);
  float4 bv = *(const float4*)(b1 + (lane<<2));
  float4 r;
  r.x = elu1(acc0*inv + bv.x);
  r.y = elu1(acc1*inv + bv.y);
  r.z = elu1(acc2*inv + bv.z);
  r.w = elu1(acc3*inv + bv.w);
  *(float4*)(out1 + ((size_t)v<<8) + (lane<<2)) = r;
}

// ---------------- conv2 linear + alphas ----------------
// h2(bf16) = out1 @ W2^T [N,64]
__global__ __launch_bounds__(256) void lin2_kernel(const float* __restrict__ in, const float* __restrict__ W2,
    const float* __restrict__ aS, const float* __restrict__ aD,
    ushort* __restrict__ h2, float* __restrict__ as2, float* __restrict__ ad2){
  __shared__ float xs[16*256]; // 16 KB
  int tid=threadIdx.x;
  int nb = blockIdx.x*16;
  {
    const float4* xsrc = (const float4*)(in + (size_t)nb*256);
    #pragma unroll
    for(int i=tid;i<16*256/4;i+=256) ((float4*)xs)[i] = xsrc[i];
  }
  __syncthreads();
  int o = tid&63; int slot = tid>>6;
  float acc[4];
  #pragma unroll
  for(int j=0;j<4;j++) acc[j]=0.f;
  const float4* Wv = (const float4*)(W2 + (size_t)o*256);
  for(int k4=0;k4<64;k4++){
    float4 w = Wv[k4];
    #pragma unroll
    for(int j=0;j<4;j++){
      float4 xv = ((const float4*)(xs + (slot*4+j)*256))[k4];
      acc[j] = fmaf(w.x,xv.x, fmaf(w.y,xv.y, fmaf(w.z,xv.z, fmaf(w.w,xv.w, acc[j]))));
    }
  }
  float asw = aS[o], adw = aD[o];
  #pragma unroll
  for(int j=0;j<4;j++){
    int n = nb + slot*4 + j;
    float h = acc[j];
    h2[(size_t)n*64 + o] = f2bf(h);
    float ps = h*asw, pd = h*adw;
    #pragma unroll
    for(int d=32; d>=1; d>>=1){ ps += __shfl_xor(ps,d); pd += __shfl_xor(pd,d); }
    if(o==0){ as2[n]=ps; ad2[n]=pd; }
  }
}

// ---------------- conv2 aggregation: 1 wave per node, no max pass ----------------
__global__ __launch_bounds__(256) void agg2_kernel(const int* __restrict__ offsets, const int* __restrict__ adj,
    const ushort* __restrict__ h2, const float* __restrict__ as2, const float* __restrict__ ad2,
    const float* __restrict__ b2, float* __restrict__ out2){
  int wv = threadIdx.x>>6, lane = threadIdx.x&63;
  int v = blockIdx.x*4 + wv;
  int start=offsets[v], end=offsets[v+1];
  float adv = ad2[v], asv = as2[v];
  float wself = __expf(lrelu(asv+adv));
  float denom = wself;
  float acc = wself * __uint_as_float((unsigned)h2[((size_t)v<<6)+lane]<<16);
  int sNext = adj[start];
  for(int i=start;i<end;i++){
    int s = sNext;
    sNext = adj[i+1];
    float w = __expf(lrelu(as2[s]+adv));
    denom += w;
    acc = fmaf(w, __uint_as_float((unsigned)h2[(((size_t)s)<<6)+lane]<<16), acc);
  }
  float r = acc/(denom+1e-16f) + b2[lane];
  out2[((size_t)v<<6)+lane] = elu1(r);
}

// ---------------- segment-max pool over batch + FC ----------------
__global__ __launch_bounds__(256) void pool_fc_kernel(const float* __restrict__ out2, const int* __restrict__ batch,
    const float* __restrict__ fcW, const float* __restrict__ fcb, float* __restrict__ out){
  int g = blockIdx.x;
  int tid=threadIdx.x; int c = tid&63; int slot = tid>>6;
  int lo=0, hi=N_NODES_C;
  while(lo<hi){ int mid=(lo+hi)>>1; if(batch[mid] < g) lo=mid+1; else hi=mid; }
  int start=lo;
  hi=N_NODES_C;
  while(lo<hi){ int mid=(lo+hi)>>1; if(batch[mid] < g+1) lo=mid+1; else hi=mid; }
  int end=lo;
  float mm = -INFINITY;
  #pragma unroll 4
  for(int n=start+slot; n<end; n+=4) mm = fmaxf(mm, out2[(size_t)n*64+c]);
  __shared__ float sred[4][64];
  sred[slot][c]=mm;
  __syncthreads();
  if(tid < 64){
    float p = fmaxf(fmaxf(sred[0][tid],sred[1][tid]), fmaxf(sred[2][tid],sred[3][tid]));
    sred[0][tid]=p;
  }
  __syncthreads();
  if(tid < OUT_DIM_C){
    float acc = fcb[tid];
    #pragma unroll
    for(int cc=0;cc<64;cc++) acc = fmaf(sred[0][cc], fcW[tid*64+cc], acc);
    out[g*OUT_DIM_C + tid] = acc;
  }
}

extern "C" void kernel_launch(void* const* d_in, const int* in_sizes, int n_in,
                              void* d_out, int out_size, void* d_ws, size_t ws_size,
                              hipStream_t stream) {
  const float* x   = (const float*)d_in[0];
  const int*   ei  = (const int*)  d_in[1];
  const int*   bat = (const int*)  d_in[2];
  const float* W1  = (const float*)d_in[3];
  const float* aS1 = (const float*)d_in[4];
  const float* aD1 = (const float*)d_in[5];
  const float* b1  = (const float*)d_in[6];
  const float* W2  = (const float*)d_in[7];
  const float* aS2 = (const float*)d_in[8];
  const float* aD2 = (const float*)d_in[9];
  const float* b2  = (const float*)d_in[10];
  const float* fcW = (const float*)d_in[11];
  const float* fcb = (const float*)d_in[12];
  float* out = (float*)d_out;

  char* w = (char*)d_ws;
  size_t off = 0;
  auto alloc = [&](size_t bytes)->char* {
    char* p = w + off; off = (off + bytes + 255) & ~(size_t)255; return p;
  };
  int* offsets   = (int*)alloc((N_NODES_C+1)*sizeof(int));
  int* cursor    = (int*)alloc((size_t)N_NODES_C*sizeof(int));
  int* blockSums = (int*)alloc(SCAN_BLOCKS*sizeof(int));
  int* adj       = (int*)alloc((size_t)(N_EDGES_C+1)*sizeof(int));  // +1: prefetch pad
  ushort* h1     = (ushort*)alloc((size_t)N_NODES_C*256*sizeof(ushort));
  float* as1     = (float*)alloc((size_t)N_NODES_C*4*sizeof(float));
  float* ad1     = (float*)alloc((size_t)N_NODES_C*4*sizeof(float));
  float* out1    = (float*)alloc((size_t)N_NODES_C*256*sizeof(float));
  ushort* h2  = h1;     // h1 dead after agg1
  float* as2  = as1;    // dead after agg1
  float* ad2  = ad1;
  float* out2 = out1;   // out1 dead after lin2
  (void)ws_size; (void)in_sizes; (void)n_in; (void)out_size;

  hipMemsetAsync(cursor, 0, (size_t)N_NODES_C*sizeof(int), stream);
  hist_kernel<<<(N_EDGES_C+255)/256, 256, 0, stream>>>(ei, cursor);
  reduce_counts<<<SCAN_BLOCKS, 256, 0, stream>>>(cursor, blockSums);
  scan_sums<<<1, 256, 0, stream>>>(blockSums);
  scan_block<<<SCAN_BLOCKS, 256, 0, stream>>>(cursor, blockSums, offsets);
  fill_kernel<<<(N_EDGES_C+255)/256, 256, 0, stream>>>(ei, cursor, adj);

  lin1_kernel<<<N_NODES_C/16, 256, 0, stream>>>(x, W1, aS1, aD1, h1, as1, ad1);
  agg1_kernel<<<N_NODES_C/4, 256, 0, stream>>>(offsets, adj, h1, as1, ad1, b1, out1);
  lin2_kernel<<<N_NODES_C/16, 256, 0, stream>>>(out1, W2, aS2, aD2, h2, as2, ad2);
  agg2_kernel<<<N_NODES_C/4, 256, 0, stream>>>(offsets, adj, h2, as2, ad2, b2, out2);
  pool_fc_kernel<<<NUM_GRAPHS_C, 256, 0, stream>>>(out2, bat, fcW, fcb, out);
}

// Round 3
// 443.678 us; speedup vs baseline: 1.8533x; 1.3301x over previous
//
#include <hip/hip_runtime.h>
#include <hip/hip_bf16.h>

#define N_NODES_C 50000
#define N_EDGES_C 800000
#define IN_DIM_C  128
#define HID_C     64
#define HEADS_C   4
#define OUT_DIM_C 20
#define NUM_GRAPHS_C 64
#define NEG_SLOPE 0.2f
#define SCAN_BLOCKS 196   // ceil(50000/256)

__device__ __forceinline__ float lrelu(float t){ return t > 0.f ? t : NEG_SLOPE*t; }
__device__ __forceinline__ float elu1(float t){ return t > 0.f ? t : __expf(t)-1.f; }
__device__ __forceinline__ ushort f2bf(float f){ // RNE f32->bf16
  unsigned u = __float_as_uint(f);
  return (ushort)((u + 0x7fffu + ((u>>16)&1u)) >> 16);
}
__device__ __forceinline__ float bflo(unsigned u){ return __uint_as_float(u<<16); }
__device__ __forceinline__ float bfhi(unsigned u){ return __uint_as_float(u & 0xffff0000u); }
__device__ __forceinline__ float bfs(ushort u){ return __uint_as_float(((unsigned)u)<<16); }

// ---------------- CSR build ----------------
__global__ void hist_kernel(const int* __restrict__ ei, int* __restrict__ cursor){
  int e = blockIdx.x*256 + threadIdx.x;
  if (e < N_EDGES_C) atomicAdd(&cursor[ei[N_EDGES_C + e]], 1);
}

__global__ __launch_bounds__(256) void reduce_counts(const int* __restrict__ cursor, int* __restrict__ blockSums){
  int i = blockIdx.x*256 + threadIdx.x;
  int c = (i < N_NODES_C) ? cursor[i] : 0;
  #pragma unroll
  for(int d=32; d>=1; d>>=1) c += __shfl_xor(c, d);
  __shared__ int s4[4];
  int lane = threadIdx.x & 63, wv = threadIdx.x >> 6;
  if(lane==0) s4[wv] = c;
  __syncthreads();
  if(threadIdx.x==0) blockSums[blockIdx.x] = s4[0]+s4[1]+s4[2]+s4[3];
}

__global__ __launch_bounds__(256) void scan_sums(int* __restrict__ blockSums){
  __shared__ int sh[256];
  int t = threadIdx.x;
  int v = (t < SCAN_BLOCKS) ? blockSums[t] : 0;
  sh[t] = v; __syncthreads();
  #pragma unroll
  for(int off=1; off<256; off<<=1){
    int u = (t>=off) ? sh[t-off] : 0;
    __syncthreads();
    sh[t] += u;
    __syncthreads();
  }
  if(t < SCAN_BLOCKS) blockSums[t] = sh[t] - v;   // exclusive
}

__global__ __launch_bounds__(256) void scan_block(int* __restrict__ cursor, const int* __restrict__ blockSums,
                                                  int* __restrict__ offsets){
  __shared__ int sh[256];
  int t = threadIdx.x;
  int i = blockIdx.x*256 + t;
  int c = (i < N_NODES_C) ? cursor[i] : 0;
  sh[t] = c; __syncthreads();
  #pragma unroll
  for(int off=1; off<256; off<<=1){
    int u = (t>=off) ? sh[t-off] : 0;
    __syncthreads();
    sh[t] += u;
    __syncthreads();
  }
  int excl = sh[t] - c;
  int pref = blockSums[blockIdx.x] + excl;
  if(i < N_NODES_C){
    offsets[i] = pref;
    cursor[i]  = pref;
    if(i == N_NODES_C-1) offsets[N_NODES_C] = pref + c;
  }
}

__global__ void fill_kernel(const int* __restrict__ ei, int* __restrict__ cursor, int* __restrict__ adj){
  int e = blockIdx.x*256 + threadIdx.x;
  if (e >= N_EDGES_C) return;
  int sI = ei[e]; int d = ei[N_EDGES_C + e];
  int p = atomicAdd(&cursor[d], 1);
  adj[p] = sI;
}

__global__ __launch_bounds__(256) void csr_dst_kernel(const int* __restrict__ offsets, int* __restrict__ dstOf){
  int v = blockIdx.x*256 + threadIdx.x;
  if (v >= N_NODES_C) return;
  int e0 = offsets[v], e1 = offsets[v+1];
  for(int i=e0;i<e1;i++) dstOf[i] = v;
}

// ---------------- weight transpose (one-time): W[O][K] -> WT[K][O] ----------------
// blocks 0..31: W1 (256x128) in 32x32 tiles (8x4); blocks 32..47: W2 (64x256) tiles (2x8)
__global__ __launch_bounds__(256) void wt_kernel(const float* __restrict__ W1, const float* __restrict__ W2,
                                                 float* __restrict__ W1T, float* __restrict__ W2T){
  __shared__ float tile[32][33];
  int b = blockIdx.x;
  const float* src; float* dst; int SC, SR;
  int tr, tc;
  if(b < 32){ src=W1; dst=W1T; SR=256; SC=128; tr=(b>>2)*32; tc=(b&3)*32; }
  else { int b2=b-32; src=W2; dst=W2T; SR=64; SC=256; tr=(b2>>3)*32; tc=(b2&7)*32; }
  int t = threadIdx.x; int r = t>>5, c = t&31;
  #pragma unroll
  for(int j=0;j<4;j++) tile[r+j*8][c] = src[(size_t)(tr+r+j*8)*SC + tc + c];
  __syncthreads();
  #pragma unroll
  for(int j=0;j<4;j++) dst[(size_t)(tc+r+j*8)*SR + tr + c] = tile[c][r+j*8];
}

// ---------------- conv1 linear: h1(bf16)[N,256] = x @ W1^T; alphas ----------------
// W1T layout [128][256] (k-major). Block: 32 nodes x 256 outputs. Thread: lane=o-quad, wave=n-slot.
__global__ __launch_bounds__(256) void lin1_kernel(const float* __restrict__ x, const float* __restrict__ W1T,
    const float* __restrict__ aS, const float* __restrict__ aD,
    ushort* __restrict__ h1, float* __restrict__ as1, float* __restrict__ ad1){
  __shared__ float Ws[32*256];   // [k][o] chunk, 32 KB
  __shared__ float xsm[32*36];   // [n][k] chunk, pad 36
  int t = threadIdx.x;
  int othr = t & 63;   // lane: owns o = othr*4..+3
  int nthr = t >> 6;   // wave: owns n = nj*4 + nthr
  int nb = blockIdx.x * 32;
  float4 acc[8];
  #pragma unroll
  for(int j=0;j<8;j++) acc[j] = make_float4(0.f,0.f,0.f,0.f);

  for(int c=0;c<4;c++){
    {
      const float4* src = (const float4*)(W1T + c*32*256);
      float4* dst = (float4*)Ws;
      #pragma unroll
      for(int j=0;j<8;j++) dst[t + j*256] = src[t + j*256];
    }
    {
      int n = t >> 3, k4 = t & 7;
      int gn = nb + n; if (gn >= N_NODES_C) gn = N_NODES_C - 1;
      float4 v = *(const float4*)(x + (size_t)gn*IN_DIM_C + c*32 + k4*4);
      *(float4*)(xsm + n*36 + k4*4) = v;
    }
    __syncthreads();
    #pragma unroll
    for(int k4=0;k4<8;k4++){
      float4 w0 = *(const float4*)(Ws + (k4*4+0)*256 + othr*4);
      float4 w1 = *(const float4*)(Ws + (k4*4+1)*256 + othr*4);
      float4 w2 = *(const float4*)(Ws + (k4*4+2)*256 + othr*4);
      float4 w3 = *(const float4*)(Ws + (k4*4+3)*256 + othr*4);
      #pragma unroll
      for(int nj=0;nj<8;nj++){
        float4 xa = *(const float4*)(xsm + (nj*4+nthr)*36 + k4*4);  // wave-uniform broadcast
        acc[nj].x = fmaf(w0.x,xa.x, fmaf(w1.x,xa.y, fmaf(w2.x,xa.z, fmaf(w3.x,xa.w, acc[nj].x))));
        acc[nj].y = fmaf(w0.y,xa.x, fmaf(w1.y,xa.y, fmaf(w2.y,xa.z, fmaf(w3.y,xa.w, acc[nj].y))));
        acc[nj].z = fmaf(w0.z,xa.x, fmaf(w1.z,xa.y, fmaf(w2.z,xa.z, fmaf(w3.z,xa.w, acc[nj].z))));
        acc[nj].w = fmaf(w0.w,xa.x, fmaf(w1.w,xa.y, fmaf(w2.w,xa.z, fmaf(w3.w,xa.w, acc[nj].w))));
      }
    }
    __syncthreads();
  }

  float4 asv = ((const float4*)aS)[othr];   // a_src flat[o], o = head*64+c
  float4 adv = ((const float4*)aD)[othr];
  int head = othr >> 4;
  #pragma unroll
  for(int nj=0;nj<8;nj++){
    int n = nb + nj*4 + nthr;
    float4 a = acc[nj];
    float ps = a.x*asv.x + a.y*asv.y + a.z*asv.z + a.w*asv.w;
    float pd = a.x*adv.x + a.y*adv.y + a.z*adv.z + a.w*adv.w;
    #pragma unroll
    for(int d=8; d>=1; d>>=1){ ps += __shfl_xor(ps,d); pd += __shfl_xor(pd,d); }
    if(n < N_NODES_C){
      ushort4 hb;
      hb.x = f2bf(a.x); hb.y = f2bf(a.y); hb.z = f2bf(a.z); hb.w = f2bf(a.w);
      *(ushort4*)(h1 + (size_t)n*256 + othr*4) = hb;
      if((othr & 15) == 0){ as1[n*4+head] = ps; ad1[n*4+head] = pd; }
    }
  }
}

// ---------------- per-edge attention weights, conv1 (CSR order) ----------------
__global__ __launch_bounds__(256) void wexp1_kernel(const int* __restrict__ adj, const int* __restrict__ dstOf,
    const float* __restrict__ as1, const float* __restrict__ ad1, float* __restrict__ wExp){
  int i = blockIdx.x*256 + threadIdx.x;
  if(i >= N_EDGES_C) return;
  int s = adj[i], d = dstOf[i];
  float4 a = ((const float4*)as1)[s];
  float4 b = ((const float4*)ad1)[d];
  float4 w;
  w.x = __expf(lrelu(a.x+b.x));
  w.y = __expf(lrelu(a.y+b.y));
  w.z = __expf(lrelu(a.z+b.z));
  w.w = __expf(lrelu(a.w+b.w));
  ((float4*)wExp)[i] = w;
}

// ---------------- conv1 aggregation: 1 wave/node, streamed weights ----------------
__global__ __launch_bounds__(256) void agg1_kernel(const int* __restrict__ offsets, const int* __restrict__ adj,
    const float* __restrict__ wExp, const ushort* __restrict__ h1,
    const float* __restrict__ as1, const float* __restrict__ ad1,
    const float* __restrict__ b1, float* __restrict__ out1){
  int wv = threadIdx.x>>6, lane = threadIdx.x&63;
  int v = blockIdx.x*4 + wv;
  int head = lane>>4;
  int start = offsets[v], end = offsets[v+1];
  float adh = ad1[(v<<2)+head];
  float ash = as1[(v<<2)+head];
  float wself = __expf(lrelu(ash+adh));
  float denom = wself;
  uint2 ps = *(const uint2*)(h1 + ((size_t)v<<8) + (lane<<2));
  float acc0 = wself*bflo(ps.x), acc1 = wself*bfhi(ps.x);
  float acc2 = wself*bflo(ps.y), acc3 = wself*bfhi(ps.y);
  int i = start;
  for(; i+1 < end; i += 2){
    int s0 = adj[i], s1 = adj[i+1];
    float w0 = wExp[(i<<2)+head];
    float w1 = wExp[((i+1)<<2)+head];
    uint2 p0 = *(const uint2*)(h1 + (((size_t)s0)<<8) + (lane<<2));
    uint2 p1 = *(const uint2*)(h1 + (((size_t)s1)<<8) + (lane<<2));
    denom += w0 + w1;
    acc0 = fmaf(w1, bflo(p1.x), fmaf(w0, bflo(p0.x), acc0));
    acc1 = fmaf(w1, bfhi(p1.x), fmaf(w0, bfhi(p0.x), acc1));
    acc2 = fmaf(w1, bflo(p1.y), fmaf(w0, bflo(p0.y), acc2));
    acc3 = fmaf(w1, bfhi(p1.y), fmaf(w0, bfhi(p0.y), acc3));
  }
  if(i < end){
    int s0 = adj[i];
    float w0 = wExp[(i<<2)+head];
    uint2 p0 = *(const uint2*)(h1 + (((size_t)s0)<<8) + (lane<<2));
    denom += w0;
    acc0 = fmaf(w0, bflo(p0.x), acc0);
    acc1 = fmaf(w0, bfhi(p0.x), acc1);
    acc2 = fmaf(w0, bflo(p0.y), acc2);
    acc3 = fmaf(w0, bfhi(p0.y), acc3);
  }
  float inv = 1.f/(denom + 1e-16f);
  float4 bv = *(const float4*)(b1 + (lane<<2));
  float4 r;
  r.x = elu1(acc0*inv + bv.x);
  r.y = elu1(acc1*inv + bv.y);
  r.z = elu1(acc2*inv + bv.z);
  r.w = elu1(acc3*inv + bv.w);
  *(float4*)(out1 + ((size_t)v<<8) + (lane<<2)) = r;
}

// ---------------- conv2 linear: h2(bf16)[N,64] = out1 @ W2^T; alphas ----------------
// W2T layout [256][64]. Block: 64 nodes x 64 outputs.
__global__ __launch_bounds__(256) void lin2_kernel(const float* __restrict__ in, const float* __restrict__ W2T,
    const float* __restrict__ aS, const float* __restrict__ aD,
    ushort* __restrict__ h2, float* __restrict__ as2, float* __restrict__ ad2){
  __shared__ float Ws[64*64];    // [k][o] chunk, 16 KB
  __shared__ float xsm[64*68];   // [n][k] chunk, pad 68
  int t = threadIdx.x;
  int othr = t & 15;   // owns o = othr*4..+3
  int nthr = t >> 4;   // owns n = nj*16 + nthr
  int nb = blockIdx.x * 64;
  float4 acc[4];
  #pragma unroll
  for(int j=0;j<4;j++) acc[j] = make_float4(0.f,0.f,0.f,0.f);

  for(int c=0;c<4;c++){
    {
      const float4* src = (const float4*)(W2T + c*64*64);
      float4* dst = (float4*)Ws;
      #pragma unroll
      for(int j=0;j<4;j++) dst[t + j*256] = src[t + j*256];
    }
    {
      #pragma unroll
      for(int j=0;j<4;j++){
        int idx = t + j*256;
        int n = idx >> 4, k4 = idx & 15;
        int gn = nb + n; if (gn >= N_NODES_C) gn = N_NODES_C - 1;
        float4 v = *(const float4*)(in + (size_t)gn*256 + c*64 + k4*4);
        *(float4*)(xsm + n*68 + k4*4) = v;
      }
    }
    __syncthreads();
    #pragma unroll
    for(int k4=0;k4<16;k4++){
      float4 w0 = *(const float4*)(Ws + (k4*4+0)*64 + othr*4);
      float4 w1 = *(const float4*)(Ws + (k4*4+1)*64 + othr*4);
      float4 w2 = *(const float4*)(Ws + (k4*4+2)*64 + othr*4);
      float4 w3 = *(const float4*)(Ws + (k4*4+3)*64 + othr*4);
      #pragma unroll
      for(int nj=0;nj<4;nj++){
        float4 xa = *(const float4*)(xsm + (nj*16+nthr)*68 + k4*4);
        acc[nj].x = fmaf(w0.x,xa.x, fmaf(w1.x,xa.y, fmaf(w2.x,xa.z, fmaf(w3.x,xa.w, acc[nj].x))));
        acc[nj].y = fmaf(w0.y,xa.x, fmaf(w1.y,xa.y, fmaf(w2.y,xa.z, fmaf(w3.y,xa.w, acc[nj].y))));
        acc[nj].z = fmaf(w0.z,xa.x, fmaf(w1.z,xa.y, fmaf(w2.z,xa.z, fmaf(w3.z,xa.w, acc[nj].z))));
        acc[nj].w = fmaf(w0.w,xa.x, fmaf(w1.w,xa.y, fmaf(w2.w,xa.z, fmaf(w3.w,xa.w, acc[nj].w))));
      }
    }
    __syncthreads();
  }

  float4 asv = ((const float4*)aS)[othr];
  float4 adv = ((const float4*)aD)[othr];
  #pragma unroll
  for(int nj=0;nj<4;nj++){
    int n = nb + nj*16 + nthr;
    float4 a = acc[nj];
    float ps = a.x*asv.x + a.y*asv.y + a.z*asv.z + a.w*asv.w;
    float pd = a.x*adv.x + a.y*adv.y + a.z*adv.z + a.w*adv.w;
    #pragma unroll
    for(int d=8; d>=1; d>>=1){ ps += __shfl_xor(ps,d); pd += __shfl_xor(pd,d); }
    if(n < N_NODES_C){
      ushort4 hb;
      hb.x = f2bf(a.x); hb.y = f2bf(a.y); hb.z = f2bf(a.z); hb.w = f2bf(a.w);
      *(ushort4*)(h2 + (size_t)n*64 + othr*4) = hb;
      if(othr == 0){ as2[n] = ps; ad2[n] = pd; }
    }
  }
}

// ---------------- per-edge attention weights, conv2 ----------------
__global__ __launch_bounds__(256) void wexp2_kernel(const int* __restrict__ adj, const int* __restrict__ dstOf,
    const float* __restrict__ as2, const float* __restrict__ ad2, float* __restrict__ wExp2){
  int i = blockIdx.x*256 + threadIdx.x;
  if(i >= N_EDGES_C) return;
  int s = adj[i], d = dstOf[i];
  wExp2[i] = __expf(lrelu(as2[s] + ad2[d]));
}

// ---------------- conv2 aggregation: 1 wave/node ----------------
__global__ __launch_bounds__(256) void agg2_kernel(const int* __restrict__ offsets, const int* __restrict__ adj,
    const float* __restrict__ wExp2, const ushort* __restrict__ h2,
    const float* __restrict__ as2, const float* __restrict__ ad2,
    const float* __restrict__ b2, float* __restrict__ out2){
  int wv = threadIdx.x>>6, lane = threadIdx.x&63;
  int v = blockIdx.x*4 + wv;
  int start = offsets[v], end = offsets[v+1];
  float adv = ad2[v], asv = as2[v];
  float wself = __expf(lrelu(asv+adv));
  float denom = wself;
  float acc = wself * bfs(h2[((size_t)v<<6)+lane]);
  int i = start;
  for(; i+1 < end; i += 2){
    int s0 = adj[i], s1 = adj[i+1];
    float w0 = wExp2[i], w1 = wExp2[i+1];
    float p0 = bfs(h2[(((size_t)s0)<<6)+lane]);
    float p1 = bfs(h2[(((size_t)s1)<<6)+lane]);
    denom += w0 + w1;
    acc = fmaf(w1, p1, fmaf(w0, p0, acc));
  }
  if(i < end){
    int s0 = adj[i];
    float w0 = wExp2[i];
    denom += w0;
    acc = fmaf(w0, bfs(h2[(((size_t)s0)<<6)+lane]), acc);
  }
  float r = acc/(denom+1e-16f) + b2[lane];
  out2[((size_t)v<<6)+lane] = elu1(r);
}

// ---------------- segment-max pool over batch + FC ----------------
__global__ __launch_bounds__(256) void pool_fc_kernel(const float* __restrict__ out2, const int* __restrict__ batch,
    const float* __restrict__ fcW, const float* __restrict__ fcb, float* __restrict__ out){
  int g = blockIdx.x;
  int tid=threadIdx.x; int c = tid&63; int slot = tid>>6;
  int lo=0, hi=N_NODES_C;
  while(lo<hi){ int mid=(lo+hi)>>1; if(batch[mid] < g) lo=mid+1; else hi=mid; }
  int start=lo;
  hi=N_NODES_C;
  while(lo<hi){ int mid=(lo+hi)>>1; if(batch[mid] < g+1) lo=mid+1; else hi=mid; }
  int end=lo;
  float mm = -INFINITY;
  #pragma unroll 4
  for(int n=start+slot; n<end; n+=4) mm = fmaxf(mm, out2[(size_t)n*64+c]);
  __shared__ float sred[4][64];
  sred[slot][c]=mm;
  __syncthreads();
  if(tid < 64){
    float p = fmaxf(fmaxf(sred[0][tid],sred[1][tid]), fmaxf(sred[2][tid],sred[3][tid]));
    sred[0][tid]=p;
  }
  __syncthreads();
  if(tid < OUT_DIM_C){
    float acc = fcb[tid];
    #pragma unroll
    for(int cc=0;cc<64;cc++) acc = fmaf(sred[0][cc], fcW[tid*64+cc], acc);
    out[g*OUT_DIM_C + tid] = acc;
  }
}

extern "C" void kernel_launch(void* const* d_in, const int* in_sizes, int n_in,
                              void* d_out, int out_size, void* d_ws, size_t ws_size,
                              hipStream_t stream) {
  const float* x   = (const float*)d_in[0];
  const int*   ei  = (const int*)  d_in[1];
  const int*   bat = (const int*)  d_in[2];
  const float* W1  = (const float*)d_in[3];
  const float* aS1 = (const float*)d_in[4];
  const float* aD1 = (const float*)d_in[5];
  const float* b1  = (const float*)d_in[6];
  const float* W2  = (const float*)d_in[7];
  const float* aS2 = (const float*)d_in[8];
  const float* aD2 = (const float*)d_in[9];
  const float* b2  = (const float*)d_in[10];
  const float* fcW = (const float*)d_in[11];
  const float* fcb = (const float*)d_in[12];
  float* out = (float*)d_out;

  char* w = (char*)d_ws;
  size_t off = 0;
  auto alloc = [&](size_t bytes)->char* {
    char* p = w + off; off = (off + bytes + 255) & ~(size_t)255; return p;
  };
  int* offsets   = (int*)alloc((N_NODES_C+1)*sizeof(int));
  int* cursor    = (int*)alloc((size_t)N_NODES_C*sizeof(int));
  int* blockSums = (int*)alloc(SCAN_BLOCKS*sizeof(int));
  int* adj       = (int*)alloc((size_t)(N_EDGES_C+1)*sizeof(int));
  int* dstOf     = (int*)alloc((size_t)N_EDGES_C*sizeof(int));
  float* W1T     = (float*)alloc((size_t)IN_DIM_C*256*sizeof(float));
  float* W2T     = (float*)alloc((size_t)256*64*sizeof(float));
  ushort* h1     = (ushort*)alloc((size_t)N_NODES_C*256*sizeof(ushort));
  float* as1     = (float*)alloc((size_t)N_NODES_C*4*sizeof(float));
  float* ad1     = (float*)alloc((size_t)N_NODES_C*4*sizeof(float));
  float* out1    = (float*)alloc((size_t)N_NODES_C*256*sizeof(float));
  float* wExp    = (float*)alloc(((size_t)N_EDGES_C*4+4)*sizeof(float));
  ushort* h2  = h1;     // h1 dead after agg1
  float* as2  = as1;    // dead after wexp1/agg1
  float* ad2  = ad1;
  float* out2 = out1;   // out1 dead after lin2
  float* wExp2 = wExp;  // dead after agg1
  (void)ws_size; (void)in_sizes; (void)n_in; (void)out_size;

  hipMemsetAsync(cursor, 0, (size_t)N_NODES_C*sizeof(int), stream);
  hist_kernel<<<(N_EDGES_C+255)/256, 256, 0, stream>>>(ei, cursor);
  reduce_counts<<<SCAN_BLOCKS, 256, 0, stream>>>(cursor, blockSums);
  scan_sums<<<1, 256, 0, stream>>>(blockSums);
  scan_block<<<SCAN_BLOCKS, 256, 0, stream>>>(cursor, blockSums, offsets);
  fill_kernel<<<(N_EDGES_C+255)/256, 256, 0, stream>>>(ei, cursor, adj);
  csr_dst_kernel<<<SCAN_BLOCKS, 256, 0, stream>>>(offsets, dstOf);
  wt_kernel<<<48, 256, 0, stream>>>(W1, W2, W1T, W2T);

  lin1_kernel<<<(N_NODES_C+31)/32, 256, 0, stream>>>(x, W1T, aS1, aD1, h1, as1, ad1);
  wexp1_kernel<<<(N_EDGES_C+255)/256, 256, 0, stream>>>(adj, dstOf, as1, ad1, wExp);
  agg1_kernel<<<N_NODES_C/4, 256, 0, stream>>>(offsets, adj, wExp, h1, as1, ad1, b1, out1);
  lin2_kernel<<<(N_NODES_C+63)/64, 256, 0, stream>>>(out1, W2T, aS2, aD2, h2, as2, ad2);
  wexp2_kernel<<<(N_EDGES_C+255)/256, 256, 0, stream>>>(adj, dstOf, as2, ad2, wExp2);
  agg2_kernel<<<N_NODES_C/4, 256, 0, stream>>>(offsets, adj, wExp2, h2, as2, ad2, b2, out2);
  pool_fc_kernel<<<NUM_GRAPHS_C, 256, 0, stream>>>(out2, bat, fcW, fcb, out);
}